// Round 3
// baseline (1156.068 us; speedup 1.0000x reference)
//
#include <hip/hip_runtime.h>
#include <math.h>

// GCN 2-layer, bucketed-LDS aggregation (no per-node CSR, no fp global atomics).
// out = Anorm( relu(Anorm(x@W1)+b1) @ W2 ) + b2,  Anorm = D^-1/2 (A+I) D^-1/2.
// dinv[src] folded into GEMM epilogues; aggregation = plain sum of scaled rows.
// Edges binned into 256-node dst-buckets; per-bucket block accumulates in LDS.

#define THREADS 256
#define BSHIFT 8
#define BROWS 256

// ---------------- edge-index dtype detection ----------------
__global__ __launch_bounds__(THREADS) void k_detect(const int* __restrict__ idx,
                                                    int E, int* __restrict__ flag) {
    __shared__ int nz;
    if (threadIdx.x == 0) nz = 0;
    __syncthreads();
    int n = (E < 1024) ? E : 1024;
    for (int i = threadIdx.x; i < n; i += blockDim.x)
        if (idx[2 * i + 1] != 0) nz = 1;  // benign race
    __syncthreads();
    if (threadIdx.x == 0) *flag = (nz == 0) ? 1 : 0;  // 1 -> int64 layout
}

__global__ __launch_bounds__(THREADS) void k_zero_i(int* __restrict__ p, int n) {
    int i = blockIdx.x * blockDim.x + threadIdx.x;
    if (i < n) p[i] = 0;
}

// ---------------- coarse histogram of dst>>8 (LDS-aggregated) ----------------
__global__ __launch_bounds__(THREADS) void k_hist(const int* __restrict__ idx, int E,
                                                  const int* __restrict__ flag,
                                                  int* __restrict__ bcnt, int NB) {
    extern __shared__ int lh[];
    for (int t = threadIdx.x; t < NB; t += THREADS) lh[t] = 0;
    __syncthreads();
    int is64 = *flag;
    int chunk = (E + gridDim.x - 1) / gridDim.x;
    int start = blockIdx.x * chunk;
    int end = min(start + chunk, E);
    for (int e = start + threadIdx.x; e < end; e += THREADS) {
        int d = is64 ? idx[2 * E + 2 * e] : idx[E + e];
        atomicAdd(&lh[d >> BSHIFT], 1);
    }
    __syncthreads();
    for (int t = threadIdx.x; t < NB; t += THREADS)
        if (lh[t]) atomicAdd(&bcnt[t], lh[t]);
}

// ---------------- exclusive scan of bucket counts (1 block) ----------------
__global__ __launch_bounds__(THREADS) void k_scan_buckets(const int* __restrict__ cnt,
                                                          int* __restrict__ off,
                                                          int* __restrict__ cursor, int NB) {
    __shared__ int wsum[4];
    __shared__ int carry_s;
    if (threadIdx.x == 0) carry_s = 0;
    __syncthreads();
    int t = threadIdx.x, lane = t & 63, w = t >> 6;
    for (int base = 0; base < NB; base += THREADS) {
        int i = base + t;
        int raw = (i < NB) ? cnt[i] : 0;
        int v = raw;
#pragma unroll
        for (int o = 1; o < 64; o <<= 1) {
            int u = __shfl_up(v, o);
            if (lane >= o) v += u;
        }
        if (lane == 63) wsum[w] = v;
        __syncthreads();
        int c0 = carry_s;
        int wadd = 0;
#pragma unroll
        for (int k = 0; k < 4; ++k) if (k < w) wadd += wsum[k];
        int excl = v - raw + wadd + c0;
        if (i < NB) { off[i] = excl; cursor[i] = excl; }
        __syncthreads();
        if (t == 0) carry_s += wsum[0] + wsum[1] + wsum[2] + wsum[3];
        __syncthreads();
    }
    if (t == 0) off[NB] = carry_s;  // == E
}

// ---------------- block-binned partition into (src,dst) pairs ----------------
__global__ __launch_bounds__(THREADS) void k_partition(const int* __restrict__ idx, int E,
                                                       const int* __restrict__ flag,
                                                       int* __restrict__ cursor,
                                                       uint2* __restrict__ pairs, int NB) {
    extern __shared__ int sm[];
    int* lhist = sm;        // NB
    int* lbase = sm + NB;   // NB
    for (int t = threadIdx.x; t < NB; t += THREADS) lhist[t] = 0;
    __syncthreads();
    int is64 = *flag;
    int chunk = (E + gridDim.x - 1) / gridDim.x;
    int start = blockIdx.x * chunk;
    int end = min(start + chunk, E);
    // pass 1: local counts
    for (int e = start + threadIdx.x; e < end; e += THREADS) {
        int d = is64 ? idx[2 * E + 2 * e] : idx[E + e];
        atomicAdd(&lhist[d >> BSHIFT], 1);
    }
    __syncthreads();
    // reserve global ranges, reset local cursors
    for (int t = threadIdx.x; t < NB; t += THREADS) {
        int c = lhist[t];
        if (c) lbase[t] = atomicAdd(&cursor[t], c);
        lhist[t] = 0;
    }
    __syncthreads();
    // pass 2: write pairs into reserved ranges
    for (int e = start + threadIdx.x; e < end; e += THREADS) {
        int s = is64 ? idx[2 * e] : idx[e];
        int d = is64 ? idx[2 * E + 2 * e] : idx[E + e];
        int b = d >> BSHIFT;
        int r = atomicAdd(&lhist[b], 1);
        pairs[lbase[b] + r] = make_uint2((unsigned)s, (unsigned)d);
    }
}

// ---------------- per-bucket degree -> dinv (no global atomics) ----------------
__global__ __launch_bounds__(THREADS) void k_deg_dinv(const uint2* __restrict__ pairs,
                                                      const int* __restrict__ boff,
                                                      float* __restrict__ dinv, int N) {
    __shared__ int cnt[BROWS];
    cnt[threadIdx.x] = 0;
    __syncthreads();
    int b = blockIdx.x;
    int start = boff[b], end = boff[b + 1];
    for (int j = start + threadIdx.x; j < end; j += THREADS)
        atomicAdd(&cnt[pairs[j].y & (BROWS - 1)], 1);
    __syncthreads();
    int node = (b << BSHIFT) + threadIdx.x;
    if (node < N) dinv[node] = rsqrtf((float)(cnt[threadIdx.x] + 1));
}

// ---------------- GEMM1: h1s = dinv[row] * (x @ W1)   [N,128]@[128,64] ----------------
__global__ __launch_bounds__(THREADS) void k_gemm1(const float* __restrict__ x,
                                                   const float* __restrict__ W,
                                                   const float* __restrict__ dinv,
                                                   float* __restrict__ h, int N) {
    __shared__ float xs[64][68];
    __shared__ float ws[64][64];
    const int tid = threadIdx.x;
    const int brow = blockIdx.x * 64;
    const int lane = tid & 63, wv = tid >> 6;
    const int jc = (lane & 15) << 2;
    const int rb = (lane >> 4) + (wv << 2);
    float4 acc[4];
    acc[0] = acc[1] = acc[2] = acc[3] = make_float4(0.f, 0.f, 0.f, 0.f);

    for (int kt = 0; kt < 128; kt += 64) {
        for (int f = tid; f < 64 * 16; f += THREADS) {
            int r = f >> 4, k4 = (f & 15) << 2;
            int row = brow + r;
            float4 v = make_float4(0.f, 0.f, 0.f, 0.f);
            if (row < N) v = *(const float4*)&x[(size_t)row * 128 + kt + k4];
            *(float4*)&xs[r][k4] = v;
        }
        for (int f = tid; f < 64 * 16; f += THREADS) {
            int k = f >> 4, c4 = (f & 15) << 2;
            *(float4*)&ws[k][c4] = *(const float4*)&W[(size_t)(kt + k) * 64 + c4];
        }
        __syncthreads();
#pragma unroll
        for (int k = 0; k < 64; k += 4) {
            float4 a[4], b[4];
#pragma unroll
            for (int i = 0; i < 4; ++i) a[i] = *(const float4*)&xs[rb + (i << 4)][k];
#pragma unroll
            for (int kk = 0; kk < 4; ++kk) b[kk] = *(const float4*)&ws[k + kk][jc];
#pragma unroll
            for (int i = 0; i < 4; ++i) {
                const float* ai = (const float*)&a[i];
#pragma unroll
                for (int kk = 0; kk < 4; ++kk) {
                    float av = ai[kk];
                    acc[i].x += av * b[kk].x;
                    acc[i].y += av * b[kk].y;
                    acc[i].z += av * b[kk].z;
                    acc[i].w += av * b[kk].w;
                }
            }
        }
        __syncthreads();
    }
#pragma unroll
    for (int i = 0; i < 4; ++i) {
        int row = brow + rb + (i << 4);
        if (row < N) {
            float dn = dinv[row];
            acc[i].x *= dn; acc[i].y *= dn; acc[i].z *= dn; acc[i].w *= dn;
            *(float4*)&h[(size_t)row * 64 + jc] = acc[i];
        }
    }
}

// ---------------- bucketed LDS aggregation ----------------
// block = (bucket, feature-slice of F). acc[256][F+1] in LDS, ds_add_f32.
// o[n] = dinv[n]*(sum_nbr hs[src] + hs[n]) + bias   (hs already has dinv[src] folded)
template <int F>
__global__ __launch_bounds__(THREADS) void k_agg_lds(const uint2* __restrict__ pairs,
                                                     const int* __restrict__ boff,
                                                     const float* __restrict__ dinv,
                                                     const float* __restrict__ hs,
                                                     const float* __restrict__ bias,
                                                     float* __restrict__ o, int N, int Ftot) {
    __shared__ float acc[BROWS][F + 1];
    for (int f = threadIdx.x; f < BROWS * (F + 1); f += THREADS)
        ((float*)acc)[f] = 0.f;
    __syncthreads();
    const int b = blockIdx.x;
    const int fbase = blockIdx.y * F;
    const int start = boff[b], end = boff[b + 1];
    const int EPW = 64 / F;  // edges per wave
    const int wid = threadIdx.x >> 6;
    const int lane = threadIdx.x & 63;
    const int sub = lane >> (6 - __builtin_ctz(EPW * F) + __builtin_ctz(F));  // lane / F
    const int i = lane & (F - 1);
    for (int j = start + wid * EPW + (lane / F); j < end; j += 4 * EPW) {
        uint2 p = pairs[j];
        float v = hs[(size_t)p.x * Ftot + fbase + i];
        atomicAdd(&acc[p.y & (BROWS - 1)][i], v);
    }
    __syncthreads();
    const int nbase = b << BSHIFT;
    for (int f = threadIdx.x; f < BROWS * F; f += THREADS) {
        int row = f / F, i2 = f & (F - 1);
        int node = nbase + row;
        if (node < N) {
            float dn = dinv[node];
            float self = hs[(size_t)node * Ftot + fbase + i2];
            o[(size_t)node * Ftot + fbase + i2] =
                dn * (acc[row][i2] + self) + bias[fbase + i2];
        }
    }
}

// ---------------- GEMM2: h2s = dinv[row] * (relu(o1) @ W2)  [N,64]@[64,32] ----------------
__global__ __launch_bounds__(THREADS) void k_gemm2(const float* __restrict__ a_in,
                                                   const float* __restrict__ W,
                                                   const float* __restrict__ dinv,
                                                   float* __restrict__ h, int N) {
    __shared__ float xs[128][68];
    __shared__ float ws[64][32];
    const int tid = threadIdx.x;
    const int brow = blockIdx.x * 128;
    for (int f = tid; f < 128 * 16; f += THREADS) {
        int r = f >> 4, k4 = (f & 15) << 2;
        int row = brow + r;
        float4 v = make_float4(0.f, 0.f, 0.f, 0.f);
        if (row < N) {
            v = *(const float4*)&a_in[(size_t)row * 64 + k4];
            v.x = fmaxf(v.x, 0.f); v.y = fmaxf(v.y, 0.f);
            v.z = fmaxf(v.z, 0.f); v.w = fmaxf(v.w, 0.f);
        }
        *(float4*)&xs[r][k4] = v;
    }
    for (int f = tid; f < 64 * 8; f += THREADS) {
        int k = f >> 3, c4 = (f & 7) << 2;
        *(float4*)&ws[k][c4] = *(const float4*)&W[(size_t)k * 32 + c4];
    }
    __syncthreads();
    const int lane = tid & 63, wv = tid >> 6;
    const int jc = (lane & 7) << 2;
    const int rb = (lane >> 3) + (wv << 3);
    float4 acc[4];
    acc[0] = acc[1] = acc[2] = acc[3] = make_float4(0.f, 0.f, 0.f, 0.f);
#pragma unroll
    for (int k = 0; k < 64; k += 4) {
        float4 a[4], b[4];
#pragma unroll
        for (int i = 0; i < 4; ++i) a[i] = *(const float4*)&xs[rb + (i << 5)][k];
#pragma unroll
        for (int kk = 0; kk < 4; ++kk) b[kk] = *(const float4*)&ws[k + kk][jc];
#pragma unroll
        for (int i = 0; i < 4; ++i) {
            const float* ai = (const float*)&a[i];
#pragma unroll
            for (int kk = 0; kk < 4; ++kk) {
                float av = ai[kk];
                acc[i].x += av * b[kk].x;
                acc[i].y += av * b[kk].y;
                acc[i].z += av * b[kk].z;
                acc[i].w += av * b[kk].w;
            }
        }
    }
#pragma unroll
    for (int i = 0; i < 4; ++i) {
        int row = brow + rb + (i << 5);
        if (row < N) {
            float dn = dinv[row];
            acc[i].x *= dn; acc[i].y *= dn; acc[i].z *= dn; acc[i].w *= dn;
            *(float4*)&h[(size_t)row * 32 + jc] = acc[i];
        }
    }
}

extern "C" void kernel_launch(void* const* d_in, const int* in_sizes, int n_in,
                              void* d_out, int out_size, void* d_ws, size_t ws_size,
                              hipStream_t stream) {
    const int N = in_sizes[0] / 128;
    const int E = in_sizes[1] / 2;
    const float* x  = (const float*)d_in[0];
    const int*   ei = (const int*)d_in[1];
    const float* W1 = (const float*)d_in[2];
    const float* b1 = (const float*)d_in[3];
    const float* W2 = (const float*)d_in[4];
    const float* b2 = (const float*)d_in[5];
    float* out = (float*)d_out;

    const int NB = (N + BROWS - 1) >> BSHIFT;

    // workspace carve (keep 8B alignment for pairs: 161N and 2E are even)
    float* dinv   = (float*)d_ws;                  // N
    float* h1s    = dinv + N;                      // N*64
    float* o1     = h1s + (size_t)N * 64;          // N*64
    float* h2s    = o1 + (size_t)N * 64;           // N*32
    uint2* pairs  = (uint2*)(h2s + (size_t)N * 32);// E (uint2)
    int*   bcnt   = (int*)(pairs + E);             // NB
    int*   boff   = bcnt + NB;                     // NB+1
    int*   cursor = boff + NB + 1;                 // NB
    int*   flag   = cursor + NB;                   // 1

    k_detect<<<1, THREADS, 0, stream>>>(ei, E, flag);
    k_zero_i<<<(NB + THREADS - 1) / THREADS, THREADS, 0, stream>>>(bcnt, NB);
    k_hist<<<512, THREADS, NB * 4, stream>>>(ei, E, flag, bcnt, NB);
    k_scan_buckets<<<1, THREADS, 0, stream>>>(bcnt, boff, cursor, NB);
    k_partition<<<512, THREADS, 2 * NB * 4, stream>>>(ei, E, flag, cursor, pairs, NB);
    k_deg_dinv<<<NB, THREADS, 0, stream>>>(pairs, boff, dinv, N);

    k_gemm1<<<(N + 63) / 64, THREADS, 0, stream>>>(x, W1, dinv, h1s, N);
    k_agg_lds<32><<<dim3(NB, 2), THREADS, 0, stream>>>(pairs, boff, dinv, h1s, b1, o1, N, 64);

    k_gemm2<<<(N + 127) / 128, THREADS, 0, stream>>>(o1, W2, dinv, h2s, N);
    k_agg_lds<16><<<dim3(NB, 2), THREADS, 0, stream>>>(pairs, boff, dinv, h2s, b2, out, N, 32);
}

// Round 4
// 256.679 us; speedup vs baseline: 4.5039x; 4.5039x over previous
//
#include <hip/hip_runtime.h>
#include <math.h>

// GCN 2-layer. CSR built via radix partition (no global cursor atomics),
// per-node-wave gather aggregation with float4 sub-group loads.
// out = Anorm( relu(Anorm(x@W1)+b1) @ W2 ) + b2,  Anorm = D^-1/2 (A+I) D^-1/2.
// dinv[src] folded into GEMM epilogues: hs = dinv[row]*(x@W);
// o[n] = dinv[n]*(sum_nbr hs[src] + hs[n]) + bias.

#define THREADS 256
#define PBLK 256      // partition blocks (must match hist chunking)
#define BSHIFT 8      // bucket = dst >> 8 (256 nodes/bucket)

// ---------------- edge-index dtype detection ----------------
__global__ __launch_bounds__(THREADS) void k_detect(const int* __restrict__ idx,
                                                    int E, int* __restrict__ flag) {
    __shared__ int nz;
    if (threadIdx.x == 0) nz = 0;
    __syncthreads();
    int n = (E < 1024) ? E : 1024;
    for (int i = threadIdx.x; i < n; i += blockDim.x)
        if (idx[2 * i + 1] != 0) nz = 1;  // benign race
    __syncthreads();
    if (threadIdx.x == 0) *flag = (nz == 0) ? 1 : 0;  // 1 -> int64 layout
}

// ---------------- per-block bucket histogram ----------------
__global__ __launch_bounds__(THREADS) void k_hist(const int* __restrict__ idx, int E,
                                                  const int* __restrict__ flag,
                                                  int* __restrict__ bh, int NB) {
    extern __shared__ int lh[];
    for (int t = threadIdx.x; t < NB; t += THREADS) lh[t] = 0;
    __syncthreads();
    int is64 = *flag;
    int chunk = (E + PBLK - 1) / PBLK;
    int start = blockIdx.x * chunk;
    int end = min(start + chunk, E);
    for (int e = start + threadIdx.x; e < end; e += THREADS) {
        int d = is64 ? idx[2 * E + 2 * e] : idx[E + e];
        atomicAdd(&lh[d >> BSHIFT], 1);
    }
    __syncthreads();
    for (int t = threadIdx.x; t < NB; t += THREADS)
        bh[blockIdx.x * NB + t] = lh[t];
}

// ---------------- bucket totals (column sum over blocks) ----------------
__global__ __launch_bounds__(THREADS) void k_colsum(const int* __restrict__ bh,
                                                    int* __restrict__ bcnt, int NB) {
    for (int b = threadIdx.x; b < NB; b += THREADS) {
        int s = 0;
        for (int k = 0; k < PBLK; ++k) s += bh[k * NB + b];
        bcnt[b] = s;
    }
}

// ---------------- exclusive scan of bucket totals ----------------
__global__ __launch_bounds__(THREADS) void k_scan_buckets(const int* __restrict__ cnt,
                                                          int* __restrict__ off, int NB) {
    __shared__ int wsum[4];
    __shared__ int carry_s;
    if (threadIdx.x == 0) carry_s = 0;
    __syncthreads();
    int t = threadIdx.x, lane = t & 63, w = t >> 6;
    for (int base = 0; base < NB; base += THREADS) {
        int i = base + t;
        int raw = (i < NB) ? cnt[i] : 0;
        int v = raw;
#pragma unroll
        for (int o = 1; o < 64; o <<= 1) {
            int u = __shfl_up(v, o);
            if (lane >= o) v += u;
        }
        if (lane == 63) wsum[w] = v;
        __syncthreads();
        int c0 = carry_s;
        int wadd = 0;
#pragma unroll
        for (int k = 0; k < 4; ++k) if (k < w) wadd += wsum[k];
        if (i < NB) off[i] = v - raw + wadd + c0;
        __syncthreads();
        if (t == 0) carry_s += wsum[0] + wsum[1] + wsum[2] + wsum[3];
        __syncthreads();
    }
    if (t == 0) off[NB] = carry_s;  // == E
}

// ---------------- per-(block,bucket) base = boff[b] + prefix over blocks ----------------
__global__ __launch_bounds__(THREADS) void k_colbase(const int* __restrict__ bh,
                                                     const int* __restrict__ boff,
                                                     int* __restrict__ bbase, int NB) {
    for (int b = threadIdx.x; b < NB; b += THREADS) {
        int run = boff[b];
        for (int k = 0; k < PBLK; ++k) {
            int i = k * NB + b;
            bbase[i] = run;
            run += bh[i];
        }
    }
}

// ---------------- partition: packed (ldst<<24)|src into bucket ranges ----------------
// requires src < 2^24 (N = 100K here)
__global__ __launch_bounds__(THREADS) void k_partition(const int* __restrict__ idx, int E,
                                                       const int* __restrict__ flag,
                                                       const int* __restrict__ bbase,
                                                       unsigned* __restrict__ pairs, int NB) {
    extern __shared__ int sm[];
    int* lbase = sm;        // NB
    int* lcur  = sm + NB;   // NB
    for (int t = threadIdx.x; t < NB; t += THREADS) {
        lbase[t] = bbase[blockIdx.x * NB + t];
        lcur[t] = 0;
    }
    __syncthreads();
    int is64 = *flag;
    int chunk = (E + PBLK - 1) / PBLK;
    int start = blockIdx.x * chunk;
    int end = min(start + chunk, E);
    for (int e = start + threadIdx.x; e < end; e += THREADS) {
        int s = is64 ? idx[2 * e] : idx[e];
        int d = is64 ? idx[2 * E + 2 * e] : idx[E + e];
        int b = d >> BSHIFT;
        int r = atomicAdd(&lcur[b], 1);
        pairs[lbase[b] + r] = (unsigned)s | ((unsigned)(d & 255) << 24);
    }
}

// ---------------- per-bucket counting sort -> csr_src, row_ptr, dinv ----------------
__global__ __launch_bounds__(THREADS) void k_sort(const unsigned* __restrict__ pairs,
                                                  const int* __restrict__ boff,
                                                  int* __restrict__ csr_src,
                                                  int* __restrict__ row_ptr,
                                                  float* __restrict__ dinv, int N, int NB) {
    __shared__ int cnt[256];
    __shared__ int cur[256];
    __shared__ int wsum[4];
    const int b = blockIdx.x, t = threadIdx.x;
    const int start = boff[b], end = boff[b + 1];
    cnt[t] = 0;
    __syncthreads();
    for (int j = start + t; j < end; j += THREADS)
        atomicAdd(&cnt[pairs[j] >> 24], 1);
    __syncthreads();
    int deg = cnt[t];
    // exclusive scan of cnt over 256 threads
    int lane = t & 63, w = t >> 6;
    int v = deg;
#pragma unroll
    for (int o = 1; o < 64; o <<= 1) {
        int u = __shfl_up(v, o);
        if (lane >= o) v += u;
    }
    if (lane == 63) wsum[w] = v;
    __syncthreads();
    int wadd = 0;
#pragma unroll
    for (int k = 0; k < 4; ++k) if (k < w) wadd += wsum[k];
    int pos = start + (v - deg) + wadd;
    cur[t] = pos;
    int node = (b << BSHIFT) + t;
    if (node < N) {
        row_ptr[node] = pos;
        dinv[node] = rsqrtf((float)(deg + 1));  // +1 self loop
    }
    if (b == NB - 1 && t == 0) row_ptr[N] = end;
    __syncthreads();
    for (int j = start + t; j < end; j += THREADS) {
        unsigned p = pairs[j];
        int r = atomicAdd(&cur[p >> 24], 1);
        csr_src[r] = (int)(p & 0xFFFFFFu);
    }
}

// ---------------- GEMM1: h1s = dinv[row] * (x @ W1)   [N,128]@[128,64] ----------------
__global__ __launch_bounds__(THREADS) void k_gemm1(const float* __restrict__ x,
                                                   const float* __restrict__ W,
                                                   const float* __restrict__ dinv,
                                                   float* __restrict__ h, int N) {
    __shared__ float xs[64][68];
    __shared__ float ws[64][64];
    const int tid = threadIdx.x;
    const int brow = blockIdx.x * 64;
    const int lane = tid & 63, wv = tid >> 6;
    const int jc = (lane & 15) << 2;
    const int rb = (lane >> 4) + (wv << 2);
    float4 acc[4];
    acc[0] = acc[1] = acc[2] = acc[3] = make_float4(0.f, 0.f, 0.f, 0.f);

    for (int kt = 0; kt < 128; kt += 64) {
        for (int f = tid; f < 64 * 16; f += THREADS) {
            int r = f >> 4, k4 = (f & 15) << 2;
            int row = brow + r;
            float4 v = make_float4(0.f, 0.f, 0.f, 0.f);
            if (row < N) v = *(const float4*)&x[(size_t)row * 128 + kt + k4];
            *(float4*)&xs[r][k4] = v;
        }
        for (int f = tid; f < 64 * 16; f += THREADS) {
            int k = f >> 4, c4 = (f & 15) << 2;
            *(float4*)&ws[k][c4] = *(const float4*)&W[(size_t)(kt + k) * 64 + c4];
        }
        __syncthreads();
#pragma unroll
        for (int k = 0; k < 64; k += 4) {
            float4 a[4], b[4];
#pragma unroll
            for (int i = 0; i < 4; ++i) a[i] = *(const float4*)&xs[rb + (i << 4)][k];
#pragma unroll
            for (int kk = 0; kk < 4; ++kk) b[kk] = *(const float4*)&ws[k + kk][jc];
#pragma unroll
            for (int i = 0; i < 4; ++i) {
                const float* ai = (const float*)&a[i];
#pragma unroll
                for (int kk = 0; kk < 4; ++kk) {
                    float av = ai[kk];
                    acc[i].x += av * b[kk].x;
                    acc[i].y += av * b[kk].y;
                    acc[i].z += av * b[kk].z;
                    acc[i].w += av * b[kk].w;
                }
            }
        }
        __syncthreads();
    }
#pragma unroll
    for (int i = 0; i < 4; ++i) {
        int row = brow + rb + (i << 4);
        if (row < N) {
            float dn = dinv[row];
            acc[i].x *= dn; acc[i].y *= dn; acc[i].z *= dn; acc[i].w *= dn;
            *(float4*)&h[(size_t)row * 64 + jc] = acc[i];
        }
    }
}

// ---------------- layer-1 agg: 1 wave/node, 4x16-lane quarters, float4 gathers ----------------
__global__ __launch_bounds__(THREADS) void k_agg1(const int* __restrict__ row_ptr,
                                                  const int* __restrict__ csr,
                                                  const float* __restrict__ dinv,
                                                  const float* __restrict__ hs,
                                                  const float* __restrict__ bias,
                                                  float* __restrict__ o, int N) {
    int wid = (blockIdx.x * blockDim.x + threadIdx.x) >> 6;
    if (wid >= N) return;
    int lane = threadIdx.x & 63;
    int q = lane >> 4, fl = lane & 15;
    int start = row_ptr[wid], end = row_ptr[wid + 1];
    float4 acc = make_float4(0.f, 0.f, 0.f, 0.f);
    for (int j = start + q; j < end; j += 4) {
        int s = csr[j];
        float4 v = *(const float4*)&hs[(size_t)s * 64 + (fl << 2)];
        acc.x += v.x; acc.y += v.y; acc.z += v.z; acc.w += v.w;
    }
    acc.x += __shfl_xor(acc.x, 16); acc.y += __shfl_xor(acc.y, 16);
    acc.z += __shfl_xor(acc.z, 16); acc.w += __shfl_xor(acc.w, 16);
    acc.x += __shfl_xor(acc.x, 32); acc.y += __shfl_xor(acc.y, 32);
    acc.z += __shfl_xor(acc.z, 32); acc.w += __shfl_xor(acc.w, 32);
    if (lane < 16) {
        float dn = dinv[wid];
        float4 self = *(const float4*)&hs[(size_t)wid * 64 + (fl << 2)];
        float4 bb = *(const float4*)&bias[fl << 2];
        float4 r;
        r.x = dn * (acc.x + self.x) + bb.x;
        r.y = dn * (acc.y + self.y) + bb.y;
        r.z = dn * (acc.z + self.z) + bb.z;
        r.w = dn * (acc.w + self.w) + bb.w;
        *(float4*)&o[(size_t)wid * 64 + (fl << 2)] = r;
    }
}

// ---------------- GEMM2: h2s = dinv[row] * (relu(o1) @ W2)  [N,64]@[64,32] ----------------
__global__ __launch_bounds__(THREADS) void k_gemm2(const float* __restrict__ a_in,
                                                   const float* __restrict__ W,
                                                   const float* __restrict__ dinv,
                                                   float* __restrict__ h, int N) {
    __shared__ float xs[128][68];
    __shared__ float ws[64][32];
    const int tid = threadIdx.x;
    const int brow = blockIdx.x * 128;
    for (int f = tid; f < 128 * 16; f += THREADS) {
        int r = f >> 4, k4 = (f & 15) << 2;
        int row = brow + r;
        float4 v = make_float4(0.f, 0.f, 0.f, 0.f);
        if (row < N) {
            v = *(const float4*)&a_in[(size_t)row * 64 + k4];
            v.x = fmaxf(v.x, 0.f); v.y = fmaxf(v.y, 0.f);
            v.z = fmaxf(v.z, 0.f); v.w = fmaxf(v.w, 0.f);
        }
        *(float4*)&xs[r][k4] = v;
    }
    for (int f = tid; f < 64 * 8; f += THREADS) {
        int k = f >> 3, c4 = (f & 7) << 2;
        *(float4*)&ws[k][c4] = *(const float4*)&W[(size_t)k * 32 + c4];
    }
    __syncthreads();
    const int lane = tid & 63, wv = tid >> 6;
    const int jc = (lane & 7) << 2;
    const int rb = (lane >> 3) + (wv << 3);
    float4 acc[4];
    acc[0] = acc[1] = acc[2] = acc[3] = make_float4(0.f, 0.f, 0.f, 0.f);
#pragma unroll
    for (int k = 0; k < 64; k += 4) {
        float4 a[4], b[4];
#pragma unroll
        for (int i = 0; i < 4; ++i) a[i] = *(const float4*)&xs[rb + (i << 5)][k];
#pragma unroll
        for (int kk = 0; kk < 4; ++kk) b[kk] = *(const float4*)&ws[k + kk][jc];
#pragma unroll
        for (int i = 0; i < 4; ++i) {
            const float* ai = (const float*)&a[i];
#pragma unroll
            for (int kk = 0; kk < 4; ++kk) {
                float av = ai[kk];
                acc[i].x += av * b[kk].x;
                acc[i].y += av * b[kk].y;
                acc[i].z += av * b[kk].z;
                acc[i].w += av * b[kk].w;
            }
        }
    }
#pragma unroll
    for (int i = 0; i < 4; ++i) {
        int row = brow + rb + (i << 5);
        if (row < N) {
            float dn = dinv[row];
            acc[i].x *= dn; acc[i].y *= dn; acc[i].z *= dn; acc[i].w *= dn;
            *(float4*)&h[(size_t)row * 32 + jc] = acc[i];
        }
    }
}

// ---------------- layer-2 agg: 1 wave/node, 8x8-lane groups, float4 gathers ----------------
__global__ __launch_bounds__(THREADS) void k_agg2(const int* __restrict__ row_ptr,
                                                  const int* __restrict__ csr,
                                                  const float* __restrict__ dinv,
                                                  const float* __restrict__ hs,
                                                  const float* __restrict__ bias,
                                                  float* __restrict__ out, int N) {
    int wid = (blockIdx.x * blockDim.x + threadIdx.x) >> 6;
    if (wid >= N) return;
    int lane = threadIdx.x & 63;
    int g = lane >> 3, fl = lane & 7;
    int start = row_ptr[wid], end = row_ptr[wid + 1];
    float4 acc = make_float4(0.f, 0.f, 0.f, 0.f);
    for (int j = start + g; j < end; j += 8) {
        int s = csr[j];
        float4 v = *(const float4*)&hs[(size_t)s * 32 + (fl << 2)];
        acc.x += v.x; acc.y += v.y; acc.z += v.z; acc.w += v.w;
    }
    acc.x += __shfl_xor(acc.x, 8);  acc.y += __shfl_xor(acc.y, 8);
    acc.z += __shfl_xor(acc.z, 8);  acc.w += __shfl_xor(acc.w, 8);
    acc.x += __shfl_xor(acc.x, 16); acc.y += __shfl_xor(acc.y, 16);
    acc.z += __shfl_xor(acc.z, 16); acc.w += __shfl_xor(acc.w, 16);
    acc.x += __shfl_xor(acc.x, 32); acc.y += __shfl_xor(acc.y, 32);
    acc.z += __shfl_xor(acc.z, 32); acc.w += __shfl_xor(acc.w, 32);
    if (lane < 8) {
        float dn = dinv[wid];
        float4 self = *(const float4*)&hs[(size_t)wid * 32 + (fl << 2)];
        float4 bb = *(const float4*)&bias[fl << 2];
        float4 r;
        r.x = dn * (acc.x + self.x) + bb.x;
        r.y = dn * (acc.y + self.y) + bb.y;
        r.z = dn * (acc.z + self.z) + bb.z;
        r.w = dn * (acc.w + self.w) + bb.w;
        *(float4*)&out[(size_t)wid * 32 + (fl << 2)] = r;
    }
}

extern "C" void kernel_launch(void* const* d_in, const int* in_sizes, int n_in,
                              void* d_out, int out_size, void* d_ws, size_t ws_size,
                              hipStream_t stream) {
    const int N = in_sizes[0] / 128;
    const int E = in_sizes[1] / 2;
    const float* x  = (const float*)d_in[0];
    const int*   ei = (const int*)d_in[1];
    const float* W1 = (const float*)d_in[2];
    const float* b1 = (const float*)d_in[3];
    const float* W2 = (const float*)d_in[4];
    const float* b2 = (const float*)d_in[5];
    float* out = (float*)d_out;

    const int NB = (N + 255) >> BSHIFT;

    // workspace carve. pairs aliases h1s (dead until gemm1, which runs after k_sort).
    float* dinv    = (float*)d_ws;                    // N
    float* h1s     = dinv + N;                        // N*64
    float* o1      = h1s + (size_t)N * 64;            // N*64
    float* h2s     = o1 + (size_t)N * 64;             // N*32
    int*   csr_src = (int*)(h2s + (size_t)N * 32);    // E
    int*   row_ptr = csr_src + E;                     // N+1
    int*   bh      = row_ptr + N + 1;                 // PBLK*NB
    int*   bbase   = bh + (size_t)PBLK * NB;          // PBLK*NB
    int*   bcnt    = bbase + (size_t)PBLK * NB;       // NB
    int*   boff    = bcnt + NB;                       // NB+1
    int*   flag    = boff + NB + 1;                   // 1
    unsigned* pairs = (unsigned*)h1s;                 // E (aliased)

    k_detect<<<1, THREADS, 0, stream>>>(ei, E, flag);
    k_hist<<<PBLK, THREADS, NB * 4, stream>>>(ei, E, flag, bh, NB);
    k_colsum<<<1, THREADS, 0, stream>>>(bh, bcnt, NB);
    k_scan_buckets<<<1, THREADS, 0, stream>>>(bcnt, boff, NB);
    k_colbase<<<1, THREADS, 0, stream>>>(bh, boff, bbase, NB);
    k_partition<<<PBLK, THREADS, 2 * NB * 4, stream>>>(ei, E, flag, bbase, pairs, NB);
    k_sort<<<NB, THREADS, 0, stream>>>(pairs, boff, csr_src, row_ptr, dinv, N, NB);

    k_gemm1<<<(N + 63) / 64, THREADS, 0, stream>>>(x, W1, dinv, h1s, N);
    k_agg1<<<(N + 3) / 4, THREADS, 0, stream>>>(row_ptr, csr_src, dinv, h1s, b1, o1, N);

    k_gemm2<<<(N + 127) / 128, THREADS, 0, stream>>>(o1, W2, dinv, h2s, N);
    k_agg2<<<(N + 3) / 4, THREADS, 0, stream>>>(row_ptr, csr_src, dinv, h2s, b2, out, N);
}

// Round 5
// 219.878 us; speedup vs baseline: 5.2578x; 1.1674x over previous
//
#include <hip/hip_runtime.h>
#include <math.h>

// GCN 2-layer. Radix-partition CSR build (no global cursor atomics),
// per-node-wave gather aggregation; layer-1 agg fused with ReLU + GEMM2.
// out = Anorm( relu(Anorm(x@W1)+b1) @ W2 ) + b2,  Anorm = D^-1/2 (A+I) D^-1/2.
// dinv[src] folded into producer epilogues: h1s = dinv*(x@W1);
// h2s = dinv * (relu(dinv*(sum h1s + self) + b1) @ W2);
// out[n] = dinv[n]*(sum h2s[src] + h2s[n]) + b2.

#define THREADS 256
#define PBLK 256      // partition blocks (hist chunking must match)
#define BSHIFT 8      // bucket = dst >> 8 (256 nodes/bucket)

// block-local int64-layout detection (consistent across blocks: same data)
__device__ __forceinline__ int detect64_block(const int* __restrict__ idx, int E,
                                              int* s_flag) {
    if (threadIdx.x == 0) *s_flag = 1;
    __syncthreads();
    int n = (E < 1024) ? E : 1024;
    for (int i = threadIdx.x; i < n; i += THREADS)
        if (idx[2 * i + 1] != 0) *s_flag = 0;  // benign race, only 0 written
    __syncthreads();
    return *s_flag;
}

// ---------------- per-block bucket histogram (+ inline detection) ----------------
__global__ __launch_bounds__(THREADS) void k_hist(const int* __restrict__ idx, int E,
                                                  int* __restrict__ bh, int NB) {
    extern __shared__ int lh[];  // NB + 1
    int is64 = detect64_block(idx, E, &lh[NB]);
    for (int t = threadIdx.x; t < NB; t += THREADS) lh[t] = 0;
    __syncthreads();
    int chunk = (E + PBLK - 1) / PBLK;
    int start = blockIdx.x * chunk;
    int end = min(start + chunk, E);
    for (int e = start + threadIdx.x; e < end; e += THREADS) {
        int d = is64 ? idx[2 * E + 2 * e] : idx[E + e];
        atomicAdd(&lh[d >> BSHIFT], 1);
    }
    __syncthreads();
    for (int t = threadIdx.x; t < NB; t += THREADS)
        bh[blockIdx.x * NB + t] = lh[t];
}

// ---------------- meta: colsum + exclusive scan + per-(block,bucket) bases ----------------
__global__ __launch_bounds__(THREADS) void k_meta(const int* __restrict__ bh,
                                                  int* __restrict__ boff,
                                                  int* __restrict__ bbase, int NB) {
    __shared__ int cnt_s[1024];
    for (int b = threadIdx.x; b < NB; b += THREADS) {
        int s = 0;
        for (int k = 0; k < PBLK; ++k) s += bh[k * NB + b];
        cnt_s[b] = s;
    }
    __syncthreads();
    if (threadIdx.x == 0) {
        int run = 0;
        for (int b = 0; b < NB; ++b) {
            int c = cnt_s[b];
            cnt_s[b] = run;
            boff[b] = run;
            run += c;
        }
        boff[NB] = run;  // == E
    }
    __syncthreads();
    for (int b = threadIdx.x; b < NB; b += THREADS) {
        int run = cnt_s[b];
        for (int k = 0; k < PBLK; ++k) {
            int i = k * NB + b;
            bbase[i] = run;
            run += bh[i];
        }
    }
}

// ---------------- partition: packed (ldst<<24)|src into bucket ranges ----------------
// requires src < 2^24 (N = 100K here)
__global__ __launch_bounds__(THREADS) void k_partition(const int* __restrict__ idx, int E,
                                                       const int* __restrict__ bbase,
                                                       unsigned* __restrict__ pairs, int NB) {
    extern __shared__ int sm[];
    int* lbase = sm;        // NB
    int* lcur  = sm + NB;   // NB (+1 for flag)
    int is64 = detect64_block(idx, E, &lcur[NB]);
    for (int t = threadIdx.x; t < NB; t += THREADS) {
        lbase[t] = bbase[blockIdx.x * NB + t];
        lcur[t] = 0;
    }
    __syncthreads();
    int chunk = (E + PBLK - 1) / PBLK;
    int start = blockIdx.x * chunk;
    int end = min(start + chunk, E);
    for (int e = start + threadIdx.x; e < end; e += THREADS) {
        int s = is64 ? idx[2 * e] : idx[e];
        int d = is64 ? idx[2 * E + 2 * e] : idx[E + e];
        int b = d >> BSHIFT;
        int r = atomicAdd(&lcur[b], 1);
        pairs[lbase[b] + r] = (unsigned)s | ((unsigned)(d & 255) << 24);
    }
}

// ---------------- per-bucket counting sort -> csr_src, row_ptr, dinv ----------------
__global__ __launch_bounds__(THREADS) void k_sort(const unsigned* __restrict__ pairs,
                                                  const int* __restrict__ boff,
                                                  int* __restrict__ csr_src,
                                                  int* __restrict__ row_ptr,
                                                  float* __restrict__ dinv, int N, int NB) {
    __shared__ int cnt[256];
    __shared__ int cur[256];
    __shared__ int wsum[4];
    const int b = blockIdx.x, t = threadIdx.x;
    const int start = boff[b], end = boff[b + 1];
    cnt[t] = 0;
    __syncthreads();
    for (int j = start + t; j < end; j += THREADS)
        atomicAdd(&cnt[pairs[j] >> 24], 1);
    __syncthreads();
    int deg = cnt[t];
    int lane = t & 63, w = t >> 6;
    int v = deg;
#pragma unroll
    for (int o = 1; o < 64; o <<= 1) {
        int u = __shfl_up(v, o);
        if (lane >= o) v += u;
    }
    if (lane == 63) wsum[w] = v;
    __syncthreads();
    int wadd = 0;
#pragma unroll
    for (int k = 0; k < 4; ++k) if (k < w) wadd += wsum[k];
    int pos = start + (v - deg) + wadd;
    cur[t] = pos;
    int node = (b << BSHIFT) + t;
    if (node < N) {
        row_ptr[node] = pos;
        dinv[node] = rsqrtf((float)(deg + 1));  // +1 self loop
    }
    if (b == NB - 1 && t == 0) row_ptr[N] = end;
    __syncthreads();
    for (int j = start + t; j < end; j += THREADS) {
        unsigned p = pairs[j];
        int r = atomicAdd(&cur[p >> 24], 1);
        csr_src[r] = (int)(p & 0xFFFFFFu);
    }
}

// ---------------- GEMM1: h1s = dinv[row] * (x @ W1)   [N,128]@[128,64] ----------------
__global__ __launch_bounds__(THREADS) void k_gemm1(const float* __restrict__ x,
                                                   const float* __restrict__ W,
                                                   const float* __restrict__ dinv,
                                                   float* __restrict__ h, int N) {
    __shared__ float xs[64][68];
    __shared__ float ws[64][64];
    const int tid = threadIdx.x;
    const int brow = blockIdx.x * 64;
    const int lane = tid & 63, wv = tid >> 6;
    const int jc = (lane & 15) << 2;
    const int rb = (lane >> 4) + (wv << 2);
    float4 acc[4];
    acc[0] = acc[1] = acc[2] = acc[3] = make_float4(0.f, 0.f, 0.f, 0.f);

    for (int kt = 0; kt < 128; kt += 64) {
        for (int f = tid; f < 64 * 16; f += THREADS) {
            int r = f >> 4, k4 = (f & 15) << 2;
            int row = brow + r;
            float4 v = make_float4(0.f, 0.f, 0.f, 0.f);
            if (row < N) v = *(const float4*)&x[(size_t)row * 128 + kt + k4];
            *(float4*)&xs[r][k4] = v;
        }
        for (int f = tid; f < 64 * 16; f += THREADS) {
            int k = f >> 4, c4 = (f & 15) << 2;
            *(float4*)&ws[k][c4] = *(const float4*)&W[(size_t)(kt + k) * 64 + c4];
        }
        __syncthreads();
#pragma unroll
        for (int k = 0; k < 64; k += 4) {
            float4 a[4], b[4];
#pragma unroll
            for (int i = 0; i < 4; ++i) a[i] = *(const float4*)&xs[rb + (i << 4)][k];
#pragma unroll
            for (int kk = 0; kk < 4; ++kk) b[kk] = *(const float4*)&ws[k + kk][jc];
#pragma unroll
            for (int i = 0; i < 4; ++i) {
                const float* ai = (const float*)&a[i];
#pragma unroll
                for (int kk = 0; kk < 4; ++kk) {
                    float av = ai[kk];
                    acc[i].x += av * b[kk].x;
                    acc[i].y += av * b[kk].y;
                    acc[i].z += av * b[kk].z;
                    acc[i].w += av * b[kk].w;
                }
            }
        }
        __syncthreads();
    }
#pragma unroll
    for (int i = 0; i < 4; ++i) {
        int row = brow + rb + (i << 4);
        if (row < N) {
            float dn = dinv[row];
            acc[i].x *= dn; acc[i].y *= dn; acc[i].z *= dn; acc[i].w *= dn;
            *(float4*)&h[(size_t)row * 64 + jc] = acc[i];
        }
    }
}

// ---------------- fused layer-1 agg + bias + ReLU + GEMM2 epilogue ----------------
// wave/node: gather h1s rows (4x16-lane quarters, float4, unroll x2), reduce,
// o1row = dinv*(acc+self)+b1 -> relu -> LDS rowbuf -> h2s_row = dinv*(row @ W2).
__global__ __launch_bounds__(THREADS) void k_agg1f(const int* __restrict__ row_ptr,
                                                   const int* __restrict__ csr,
                                                   const float* __restrict__ dinv,
                                                   const float* __restrict__ hs,
                                                   const float* __restrict__ b1,
                                                   const float* __restrict__ W2,
                                                   float* __restrict__ h2s, int N) {
    __shared__ float w2s[64][32];   // [k][j]; 2-way wave64 aliasing is free
    __shared__ float rowbuf[4][64]; // per-wave relu(o1) row
    const int tid = threadIdx.x;
    for (int f = tid; f < 64 * 8; f += THREADS) {
        int k = f >> 3, c4 = (f & 7) << 2;
        *(float4*)&w2s[k][c4] = *(const float4*)&W2[(size_t)k * 32 + c4];
    }
    __syncthreads();

    const int wid = (blockIdx.x * THREADS + tid) >> 6;
    if (wid >= N) return;
    const int lane = tid & 63;
    const int wv = tid >> 6;
    const int q = lane >> 4, fl = lane & 15;

    int start = row_ptr[wid], end = row_ptr[wid + 1];
    float4 acc = make_float4(0.f, 0.f, 0.f, 0.f);
    int j = start + q;
    for (; j + 4 < end; j += 8) {
        int s0 = csr[j], s1 = csr[j + 4];
        float4 v0 = *(const float4*)&hs[(size_t)s0 * 64 + (fl << 2)];
        float4 v1 = *(const float4*)&hs[(size_t)s1 * 64 + (fl << 2)];
        acc.x += v0.x + v1.x; acc.y += v0.y + v1.y;
        acc.z += v0.z + v1.z; acc.w += v0.w + v1.w;
    }
    if (j < end) {
        int s = csr[j];
        float4 v = *(const float4*)&hs[(size_t)s * 64 + (fl << 2)];
        acc.x += v.x; acc.y += v.y; acc.z += v.z; acc.w += v.w;
    }
    acc.x += __shfl_xor(acc.x, 16); acc.y += __shfl_xor(acc.y, 16);
    acc.z += __shfl_xor(acc.z, 16); acc.w += __shfl_xor(acc.w, 16);
    acc.x += __shfl_xor(acc.x, 32); acc.y += __shfl_xor(acc.y, 32);
    acc.z += __shfl_xor(acc.z, 32); acc.w += __shfl_xor(acc.w, 32);

    const float dn = dinv[wid];
    if (lane < 16) {
        float4 self = *(const float4*)&hs[(size_t)wid * 64 + (fl << 2)];
        float4 bb = *(const float4*)&b1[fl << 2];
        float4 r;
        r.x = fmaxf(dn * (acc.x + self.x) + bb.x, 0.f);
        r.y = fmaxf(dn * (acc.y + self.y) + bb.y, 0.f);
        r.z = fmaxf(dn * (acc.z + self.z) + bb.z, 0.f);
        r.w = fmaxf(dn * (acc.w + self.w) + bb.w, 0.f);
        *(float4*)&rowbuf[wv][fl << 2] = r;
    }
    // same-wave LDS dependency: compiler inserts lgkmcnt wait; no barrier needed
    const int j2 = lane & 31, kh = (lane >> 5) << 5;  // k base 0 or 32
    float a2 = 0.f;
#pragma unroll
    for (int k = 0; k < 32; ++k)
        a2 += rowbuf[wv][kh + k] * w2s[kh + k][j2];
    a2 += __shfl_xor(a2, 32);
    if (lane < 32) h2s[(size_t)wid * 32 + j2] = dn * a2;
}

// ---------------- layer-2 agg: 1 wave/node, 8x8-lane groups, float4, unroll x2 ----------------
__global__ __launch_bounds__(THREADS) void k_agg2(const int* __restrict__ row_ptr,
                                                  const int* __restrict__ csr,
                                                  const float* __restrict__ dinv,
                                                  const float* __restrict__ hs,
                                                  const float* __restrict__ bias,
                                                  float* __restrict__ out, int N) {
    int wid = (blockIdx.x * blockDim.x + threadIdx.x) >> 6;
    if (wid >= N) return;
    int lane = threadIdx.x & 63;
    int g = lane >> 3, fl = lane & 7;
    int start = row_ptr[wid], end = row_ptr[wid + 1];
    float4 acc = make_float4(0.f, 0.f, 0.f, 0.f);
    int j = start + g;
    for (; j + 8 < end; j += 16) {
        int s0 = csr[j], s1 = csr[j + 8];
        float4 v0 = *(const float4*)&hs[(size_t)s0 * 32 + (fl << 2)];
        float4 v1 = *(const float4*)&hs[(size_t)s1 * 32 + (fl << 2)];
        acc.x += v0.x + v1.x; acc.y += v0.y + v1.y;
        acc.z += v0.z + v1.z; acc.w += v0.w + v1.w;
    }
    if (j < end) {
        int s = csr[j];
        float4 v = *(const float4*)&hs[(size_t)s * 32 + (fl << 2)];
        acc.x += v.x; acc.y += v.y; acc.z += v.z; acc.w += v.w;
    }
    acc.x += __shfl_xor(acc.x, 8);  acc.y += __shfl_xor(acc.y, 8);
    acc.z += __shfl_xor(acc.z, 8);  acc.w += __shfl_xor(acc.w, 8);
    acc.x += __shfl_xor(acc.x, 16); acc.y += __shfl_xor(acc.y, 16);
    acc.z += __shfl_xor(acc.z, 16); acc.w += __shfl_xor(acc.w, 16);
    acc.x += __shfl_xor(acc.x, 32); acc.y += __shfl_xor(acc.y, 32);
    acc.z += __shfl_xor(acc.z, 32); acc.w += __shfl_xor(acc.w, 32);
    if (lane < 8) {
        float dn = dinv[wid];
        float4 self = *(const float4*)&hs[(size_t)wid * 32 + (fl << 2)];
        float4 bb = *(const float4*)&bias[fl << 2];
        float4 r;
        r.x = dn * (acc.x + self.x) + bb.x;
        r.y = dn * (acc.y + self.y) + bb.y;
        r.z = dn * (acc.z + self.z) + bb.z;
        r.w = dn * (acc.w + self.w) + bb.w;
        *(float4*)&out[(size_t)wid * 32 + (fl << 2)] = r;
    }
}

extern "C" void kernel_launch(void* const* d_in, const int* in_sizes, int n_in,
                              void* d_out, int out_size, void* d_ws, size_t ws_size,
                              hipStream_t stream) {
    const int N = in_sizes[0] / 128;
    const int E = in_sizes[1] / 2;
    const float* x  = (const float*)d_in[0];
    const int*   ei = (const int*)d_in[1];
    const float* W1 = (const float*)d_in[2];
    const float* b1 = (const float*)d_in[3];
    const float* W2 = (const float*)d_in[4];
    const float* b2 = (const float*)d_in[5];
    float* out = (float*)d_out;

    const int NB = (N + 255) >> BSHIFT;

    // workspace carve. pairs aliases h1s (dead until k_gemm1, which runs after k_sort).
    float* dinv    = (float*)d_ws;                    // N
    float* h1s     = dinv + N;                        // N*64
    float* h2s     = h1s + (size_t)N * 64;            // N*32
    int*   csr_src = (int*)(h2s + (size_t)N * 32);    // E
    int*   row_ptr = csr_src + E;                     // N+1
    int*   bh      = row_ptr + N + 1;                 // PBLK*NB
    int*   bbase   = bh + (size_t)PBLK * NB;          // PBLK*NB
    int*   boff    = bbase + (size_t)PBLK * NB;       // NB+1
    unsigned* pairs = (unsigned*)h1s;                 // E (aliased)

    k_hist<<<PBLK, THREADS, (NB + 1) * 4, stream>>>(ei, E, bh, NB);
    k_meta<<<1, THREADS, 0, stream>>>(bh, boff, bbase, NB);
    k_partition<<<PBLK, THREADS, (2 * NB + 1) * 4, stream>>>(ei, E, bbase, pairs, NB);
    k_sort<<<NB, THREADS, 0, stream>>>(pairs, boff, csr_src, row_ptr, dinv, N, NB);

    k_gemm1<<<(N + 63) / 64, THREADS, 0, stream>>>(x, W1, dinv, h1s, N);
    k_agg1f<<<(N + 3) / 4, THREADS, 0, stream>>>(row_ptr, csr_src, dinv, h1s, b1, W2, h2s, N);
    k_agg2<<<(N + 3) / 4, THREADS, 0, stream>>>(row_ptr, csr_src, dinv, h2s, b2, out, N);
}